// Round 14
// baseline (643.340 us; speedup 1.0000x reference)
//
#include <hip/hip_runtime.h>

typedef __attribute__((ext_vector_type(4))) float f32x4;
typedef __attribute__((ext_vector_type(4))) unsigned int u32x4;
typedef __attribute__((ext_vector_type(8))) _Float16 half8;
typedef __attribute__((ext_vector_type(2))) _Float16 half2v;

__device__ inline f32x4 mfma_fp16(half8 a, half8 b, f32x4 c) {
  return __builtin_amdgcn_mfma_f32_16x16x32_f16(a, b, c, 0, 0, 0);
}

// XOR-swizzled element index, [rows][64 cols] fp16 tile (row stride 128B).
__device__ inline int kva(int row, int colbyte) {
  return ((row * 128 + colbyte) ^ ((row & 7) << 4)) >> 1;
}

// XOR-swizzled element index, [rows][32 cols] fp16 tile (row stride 64B).
// bank-group = (row&1)*16 ^ chunk*4 with chunk = cb ^ ((row>>1)&3) -> 2-way max.
__device__ inline int kva32(int row, int colbyte) {
  return ((row * 64) + (colbyte ^ (((row >> 1) & 3) << 4))) >> 1;
}

// async global->LDS, 16B/lane; LDS dest = wave-uniform base + lane*16 (linear).
__device__ inline void gload16(const _Float16* g, _Float16* l) {
  __builtin_amdgcn_global_load_lds(
      (const __attribute__((address_space(1))) void*)g,
      (__attribute__((address_space(3))) void*)l, 16, 0, 0);
}

// All 4 weight matrices (K x N fp32) -> transposed fp16 hi/lo planes (N x K).
// lo = UNSCALED residual.
__global__ __launch_bounds__(256) void wsplit4_kernel(
    const float* __restrict__ Wq, const float* __restrict__ Wk,
    const float* __restrict__ Wv, const float* __restrict__ Wo,
    _Float16* __restrict__ Whi, _Float16* __restrict__ Wlo) {
  int w = blockIdx.y;
  const float* W = (w == 0) ? Wq : (w == 1) ? Wk : (w == 2) ? Wv : Wo;
  int i = blockIdx.x * 256 + threadIdx.x;
  int k = i / 768, n = i % 768;
  float v = W[i];
  _Float16 h = (_Float16)v;
  Whi[w * 589824 + n * 768 + k] = h;
  Wlo[w * 589824 + n * 768 + k] = (_Float16)(v - (float)h);
}

__device__ inline void asplit_body(const float* __restrict__ A,
                                   _Float16* __restrict__ Ahi,
                                   _Float16* __restrict__ Alo, int i) {
  f32x4 x0 = *(const f32x4*)(A + i);
  f32x4 x1 = *(const f32x4*)(A + i + 4);
  half8 vh, vl;
#pragma unroll
  for (int j = 0; j < 4; ++j) {
    _Float16 h0 = (_Float16)x0[j];
    vh[j] = h0; vl[j] = (_Float16)(x0[j] - (float)h0);
    _Float16 h1 = (_Float16)x1[j];
    vh[4 + j] = h1; vl[4 + j] = (_Float16)(x1[j] - (float)h1);
  }
  *(half8*)(Ahi + i) = vh;
  *(half8*)(Alo + i) = vl;
}

__global__ __launch_bounds__(256) void asplit_kernel(const float* __restrict__ A,
                                                     _Float16* __restrict__ Ahi,
                                                     _Float16* __restrict__ Alo) {
  asplit_body(A, Ahi, Alo, (blockIdx.x * 256 + threadIdx.x) * 8);
}

__global__ __launch_bounds__(256) void asplit3_kernel(
    const float* __restrict__ Aq, const float* __restrict__ Ak,
    const float* __restrict__ Av,
    _Float16* __restrict__ Aqh, _Float16* __restrict__ Aql,
    _Float16* __restrict__ Akh, _Float16* __restrict__ Akl,
    _Float16* __restrict__ Avh, _Float16* __restrict__ Avl) {
  int w = blockIdx.y;
  const float* A = (w == 0) ? Aq : (w == 1) ? Ak : Av;
  _Float16* H = (w == 0) ? Aqh : (w == 1) ? Akh : Avh;
  _Float16* L = (w == 0) ? Aql : (w == 1) ? Akl : Avl;
  asplit_body(A, H, L, (blockIdx.x * 256 + threadIdx.x) * 8);
}

// Vt plane base (in elements) for (b, head). Per-b size = 3,670,016 elems.
__device__ inline int vt_base(int b, int h) {
  int base = b * 3670016;
  if (h < 4)      base += h * 524288;
  else if (h < 8) base += 2097152 + (h - 4) * 262144;
  else            base += 3145728 + (h - 8) * 131072;
  return base;
}

// High-precision GEMM core, fp16-pair split, merged fp32 accumulator.
// BK=32: LDS 4 x 128x32 fp16 = 32KB -> 3 blocks/CU at (512,3).
// Staging via global_load_lds (16B/lane; one gload per plane per k-step;
// linear LDS dest + pre-swizzled global source matching kva32 reads).
// nf-outer/mt-inner keeps live VGPR ~70 <= 85 cap; each acc[mt][nf] chain
// order is unchanged -> bit-identical numerics vs R13.
__device__ __forceinline__ void gemm3_core(
    const _Float16* __restrict__ Ahi, const _Float16* __restrict__ Alo,
    const _Float16* __restrict__ Bhi, const _Float16* __restrict__ Blo,
    const float* __restrict__ bias, _Float16* __restrict__ Chi,
    _Float16* __restrict__ Clo, int mode, int m0, int n0,
    _Float16* Ah, _Float16* Al, _Float16* Bh, _Float16* Bl) {
  int tid = threadIdx.x;
  int lane = tid & 63, wid = tid >> 6;
  int wm = wid >> 1, wn = wid & 1;
  int lg = lane >> 4, lc = lane & 15;

  f32x4 acc[2][4] = {};

  // deposit: thread i covers row = i>>2, chunk = i&3; source column
  // pre-XORed so linear LDS deposit realizes the kva32 layout.
  int mrow = tid >> 2;
  int ke = (((tid & 3) ^ ((tid >> 3) & 3)) << 3);
  size_t sA = (size_t)(m0 + mrow) * 768 + ke;
  size_t sB = (size_t)(n0 + mrow) * 768 + ke;
  int ldst = wid * 512;   // wave-uniform element base (64 lanes x 8 elems)

  for (int k0 = 0; k0 < 768; k0 += 32) {
    __syncthreads();
    gload16(Ahi + sA + k0, Ah + ldst);
    gload16(Alo + sA + k0, Al + ldst);
    gload16(Bhi + sB + k0, Bh + ldst);
    gload16(Blo + sB + k0, Bl + ldst);
    __syncthreads();   // vmcnt drained -> tile ready

    half8 ah[2], al[2];
#pragma unroll
    for (int mt = 0; mt < 2; ++mt) {
      int ro = kva32(wm * 32 + mt * 16 + lc, lg << 4);
      ah[mt] = *(half8*)(&Ah[ro]);
      al[mt] = *(half8*)(&Al[ro]);
    }
#pragma unroll
    for (int nf = 0; nf < 4; ++nf) {
      int ro = kva32(wn * 64 + nf * 16 + lc, lg << 4);
      half8 bh = *(half8*)(&Bh[ro]);
      half8 bl = *(half8*)(&Bl[ro]);
#pragma unroll
      for (int mt = 0; mt < 2; ++mt) {
        acc[mt][nf] = mfma_fp16(al[mt], bh, acc[mt][nf]);
        acc[mt][nf] = mfma_fp16(ah[mt], bl, acc[mt][nf]);
        acc[mt][nf] = mfma_fp16(ah[mt], bh, acc[mt][nf]);
      }
    }
  }

#pragma unroll
  for (int mt = 0; mt < 2; ++mt)
#pragma unroll
    for (int nf = 0; nf < 4; ++nf) {
      int col = n0 + wn * 64 + nf * 16 + lc;
      int row0 = m0 + wm * 32 + mt * 16 + (lg << 2);
      float bv = bias[col];
#pragma unroll
      for (int rr = 0; rr < 4; ++rr) {
        int row = row0 + rr;
        float v = acc[mt][nf][rr] + bv;
        _Float16 h = (_Float16)v;
        _Float16 l = (_Float16)(v - (float)h);
        if (mode == 0) {
          Chi[(size_t)row * 768 + col] = h;
          Clo[(size_t)row * 768 + col] = l;
        } else {
          int b = row >> 13, pos = row & 8191;
          int hh = col >> 6, d = col & 63;
          int g = hh >> 2;
          int rdil = 1 << g;
          if ((pos & (rdil - 1)) == g) {
            int t = (pos - g) >> g;
            int Ng = 8192 >> g;
            Chi[vt_base(b, hh) + d * Ng + t] = h;
            Clo[vt_base(b, hh) + d * Ng + t] = l;
          }
        }
      }
    }
}

// fallback: one projection per launch
__global__ __launch_bounds__(512, 3) void gemm3_kernel(
    const _Float16* __restrict__ Ahi, const _Float16* __restrict__ Alo,
    const _Float16* __restrict__ Bhi, const _Float16* __restrict__ Blo,
    const float* __restrict__ bias,
    _Float16* __restrict__ Chi, _Float16* __restrict__ Clo, int mode) {
  __shared__ _Float16 Ah[128 * 32], Al[128 * 32], Bh[128 * 32], Bl[128 * 32];
  gemm3_core(Ahi, Alo, Bhi, Blo, bias, Chi, Clo, mode,
             blockIdx.y * 128, blockIdx.x * 128, Ah, Al, Bh, Bl);
}

// batched: all three projections in one launch (section = blockIdx.y>>7)
__global__ __launch_bounds__(512, 3) void gemm3b_kernel(
    const _Float16* __restrict__ Aqh, const _Float16* __restrict__ Aql,
    const _Float16* __restrict__ Akh, const _Float16* __restrict__ Akl,
    const _Float16* __restrict__ Avh, const _Float16* __restrict__ Avl,
    const _Float16* __restrict__ Wsh, const _Float16* __restrict__ Wsl,
    const float* __restrict__ bq, const float* __restrict__ bk,
    const float* __restrict__ bv,
    _Float16* __restrict__ Qhb, _Float16* __restrict__ Qlb,
    _Float16* __restrict__ Khb, _Float16* __restrict__ Klb,
    _Float16* __restrict__ Vth, _Float16* __restrict__ Vtl) {
  __shared__ _Float16 Ah[128 * 32], Al[128 * 32], Bh[128 * 32], Bl[128 * 32];
  int sec = blockIdx.y >> 7;
  int m0 = (blockIdx.y & 127) * 128, n0 = blockIdx.x * 128;
  const _Float16* Ahi = (sec == 0) ? Aqh : (sec == 1) ? Akh : Avh;
  const _Float16* Alo = (sec == 0) ? Aql : (sec == 1) ? Akl : Avl;
  const float* bias = (sec == 0) ? bq : (sec == 1) ? bk : bv;
  _Float16* Chi = (sec == 0) ? Qhb : (sec == 1) ? Khb : Vth;
  _Float16* Clo = (sec == 0) ? Qlb : (sec == 1) ? Klb : Vtl;
  gemm3_core(Ahi, Alo, Wsh + sec * 589824, Wsl + sec * 589824, bias,
             Chi, Clo, (sec == 2) ? 1 : 0, m0, n0, Ah, Al, Bh, Bl);
}

// Output projection: C(fp32) = A(fp16) @ Wt^T + bias. A = post-LN X (fp16).
__global__ __launch_bounds__(256, 4) void gemm1_kernel(
    const _Float16* __restrict__ A, const _Float16* __restrict__ Bt,
    const float* __restrict__ bias, float* __restrict__ C) {
  __shared__ _Float16 As[128 * 64];
  __shared__ _Float16 Bs[128 * 64];
  int tid = threadIdx.x;
  int m0 = blockIdx.y * 128, n0 = blockIdx.x * 128;
  int lane = tid & 63, wid = tid >> 6;
  int wm = wid >> 1, wn = wid & 1;
  int lg = lane >> 4, lc = lane & 15;

  f32x4 acc[4][4] = {};

  size_t sA[4], sB[4];
  int ldst[4];
#pragma unroll
  for (int c = 0; c < 4; ++c) {
    int idxv = c * 256 + tid;
    int m = idxv >> 3;
    int ke = ((idxv & 7) << 3) ^ ((m & 7) << 3);
    sA[c] = (size_t)(m0 + m) * 768 + ke;
    sB[c] = (size_t)(n0 + m) * 768 + ke;
    ldst[c] = (c * 256 + wid * 64) * 8;
  }

  for (int k0 = 0; k0 < 768; k0 += 64) {
    __syncthreads();
#pragma unroll
    for (int c = 0; c < 4; ++c) {
      gload16(A + sA[c] + k0, As + ldst[c]);
      gload16(Bt + sB[c] + k0, Bs + ldst[c]);
    }
    __syncthreads();
#pragma unroll
    for (int ks = 0; ks < 2; ++ks) {
      half8 af[4], bf[4];
#pragma unroll
      for (int mt = 0; mt < 4; ++mt)
        af[mt] = *(half8*)(&As[kva(wm * 64 + mt * 16 + lc, ks * 64 + (lg << 4))]);
#pragma unroll
      for (int nf = 0; nf < 4; ++nf)
        bf[nf] = *(half8*)(&Bs[kva(wn * 64 + nf * 16 + lc, ks * 64 + (lg << 4))]);
#pragma unroll
      for (int mt = 0; mt < 4; ++mt)
#pragma unroll
        for (int nf = 0; nf < 4; ++nf)
          acc[mt][nf] = mfma_fp16(af[mt], bf[nf], acc[mt][nf]);
    }
  }

#pragma unroll
  for (int mt = 0; mt < 4; ++mt)
#pragma unroll
    for (int nf = 0; nf < 4; ++nf) {
      int col = n0 + wn * 64 + nf * 16 + lc;
      int row0 = m0 + wm * 64 + mt * 16 + (lg << 2);
      float bv = bias[col];
#pragma unroll
      for (int rr = 0; rr < 4; ++rr)
        C[(size_t)(row0 + rr) * 768 + col] = acc[mt][nf][rr] + bv;
    }
}

// Single-pass dilated flash attention, fp16-pair precision, merged accumulator.
// SWAPPED QK^T; PV A-frags via in-wave shfl; fp16 X; fused colsum stage 1.
__global__ __launch_bounds__(512, 4) void attn_kernel(
    const _Float16* __restrict__ Qh, const _Float16* __restrict__ Ql,
    const _Float16* __restrict__ Kh, const _Float16* __restrict__ Kl,
    const _Float16* __restrict__ Vth, const _Float16* __restrict__ Vtl,
    _Float16* __restrict__ Xh, float* __restrict__ partial) {
  __shared__ _Float16 Ksh[64 * 64], Ksl[64 * 64];   // XOR-swizzled, stride 64
  __shared__ _Float16 Vsh[64 * 64], Vsl[64 * 64];
  __shared__ float wred[8][64];

  int bid = blockIdx.x;
  int xcd = bid & 7, idx = bid >> 3;
  int u_glob = xcd * 7 + (idx >> 4);
  int qblk = idx & 15;
  int g = (u_glob < 32) ? 0 : (u_glob < 48) ? 1 : 2;
  int u = (g == 0) ? u_glob : (g == 1) ? u_glob - 32 : u_glob - 48;
  int nsegs = 4 >> g;
  int b = u / (nsegs * 4), rem = u % (nsegs * 4);
  int nseg = rem >> 2, hg = rem & 3;
  int head = g * 4 + hg;
  int s = 2048 << g, r = 1 << g, off = g;
  int Ng = 8192 >> g;
  int tbase = nseg * 2048;
  int vbase = vt_base(b, head);

  int tid = threadIdx.x, lane = tid & 63, wid = tid >> 6;
  int lg = lane >> 4, lc = lane & 15;

  int q0 = qblk * 128 + wid * 16;
  half8 qfh[2], qfl[2];
  {
    int q = q0 + lc;
    int pos = nseg * s + off + q * r;
    size_t ro = (size_t)(b * 8192 + pos) * 768 + head * 64;
#pragma unroll
    for (int ks = 0; ks < 2; ++ks) {
      qfh[ks] = *(const half8*)(Qh + ro + ks * 32 + (lg << 3));
      qfl[ks] = *(const half8*)(Ql + ro + ks * 32 + (lg << 3));
    }
  }

  int kr = tid >> 3, kcb = (tid & 7) << 4;
  const int kc = (tid & 7) << 3;
  size_t kro = (size_t)(b * 8192 + nseg * s + off + kr * r) * 768 + head * 64 + kc;
  size_t vro = (size_t)vbase + (size_t)kr * Ng + tbase + kc;
  const size_t kstep = (size_t)64 * r * 768;
  _Float16* KshW = &Ksh[kva(kr, kcb)];
  _Float16* KslW = &Ksl[kva(kr, kcb)];
  _Float16* VshW = &Vsh[kva(kr, kcb)];
  _Float16* VslW = &Vsl[kva(kr, kcb)];

  f32x4 acch[4] = {};
  float lsum = 0.f;

  const int sl0 = ((lane & 16) << 1) + lc;
  const int sl1 = sl0 + 16;
  const bool hiSel = (lane & 32) != 0;

  half8 rKh = *(const half8*)(Kh + kro);
  half8 rKl = *(const half8*)(Kl + kro);
  half8 rVh = *(const half8*)(Vth + vro);
  half8 rVl = *(const half8*)(Vtl + vro);
  kro += kstep;
  vro += 64;

  for (int kt = 0; kt < 32; ++kt) {
    __syncthreads();
    *(half8*)KshW = rKh;
    *(half8*)KslW = rKl;
    *(half8*)VshW = rVh;
    *(half8*)VslW = rVl;
    if (kt < 31) {
      rKh = *(const half8*)(Kh + kro);
      rKl = *(const half8*)(Kl + kro);
      rVh = *(const half8*)(Vth + vro);
      rVl = *(const half8*)(Vtl + vro);
      kro += kstep;
      vro += 64;
    }
    __syncthreads();

    f32x4 sc[4];
#pragma unroll
    for (int nf = 0; nf < 4; ++nf) {
      half8 kh[2], kl[2];
#pragma unroll
      for (int ks = 0; ks < 2; ++ks) {
        int ro = kva(nf * 16 + lc, ks * 64 + (lg << 4));
        kh[ks] = *(half8*)(&Ksh[ro]);
        kl[ks] = *(half8*)(&Ksl[ro]);
      }
      f32x4 t = {};
#pragma unroll
      for (int ks = 0; ks < 2; ++ks) {
        t = mfma_fp16(kl[ks], qfh[ks], t);
        t = mfma_fp16(kh[ks], qfl[ks], t);
      }
#pragma unroll
      for (int ks = 0; ks < 2; ++ks)
        t = mfma_fp16(kh[ks], qfh[ks], t);
      sc[nf] = t;
    }

    unsigned int pk[4][2];
#pragma unroll
    for (int nf = 0; nf < 4; ++nf) {
      _Float16 hh[4];
#pragma unroll
      for (int rr = 0; rr < 4; ++rr) {
        float p = __expf(sc[nf][rr] * 0.125f);
        hh[rr] = (_Float16)p;
        lsum += (float)hh[rr];
      }
      half2v p01 = {hh[0], hh[1]};
      half2v p23 = {hh[2], hh[3]};
      pk[nf][0] = __builtin_bit_cast(unsigned int, p01);
      pk[nf][1] = __builtin_bit_cast(unsigned int, p23);
    }

#pragma unroll
    for (int ks2 = 0; ks2 < 2; ++ks2) {
      int nfA = 2 * ks2, nfB = 2 * ks2 + 1;
      unsigned int a0 = __shfl(pk[nfA][0], sl0, 64);
      unsigned int b0 = __shfl(pk[nfB][0], sl0, 64);
      unsigned int a1 = __shfl(pk[nfA][1], sl0, 64);
      unsigned int b1 = __shfl(pk[nfB][1], sl0, 64);
      unsigned int a2 = __shfl(pk[nfA][0], sl1, 64);
      unsigned int b2 = __shfl(pk[nfB][0], sl1, 64);
      unsigned int a3 = __shfl(pk[nfA][1], sl1, 64);
      unsigned int b3 = __shfl(pk[nfB][1], sl1, 64);
      u32x4 pw;
      pw[0] = hiSel ? b0 : a0;
      pw[1] = hiSel ? b1 : a1;
      pw[2] = hiSel ? b2 : a2;
      pw[3] = hiSel ? b3 : a3;
      half8 pa = __builtin_bit_cast(half8, pw);
#pragma unroll
      for (int nf = 0; nf < 4; ++nf) {
        int ro = kva(nf * 16 + lc, ks2 * 64 + (lg << 4));
        half8 vh = *(half8*)(&Vsh[ro]);
        half8 vl = *(half8*)(&Vsl[ro]);
        acch[nf] = mfma_fp16(pa, vl, acch[nf]);
        acch[nf] = mfma_fp16(pa, vh, acch[nf]);
      }
    }
  }

  lsum += __shfl_xor(lsum, 16, 64);
  lsum += __shfl_xor(lsum, 32, 64);
  float inv_l = 1.0f / lsum;

  float cs[4] = {};
#pragma unroll
  for (int rr = 0; rr < 4; ++rr) {
    int qi = ((lane >> 4) & 3) * 4 + rr;
    float invq = __shfl(inv_l, (lane & 48) + qi, 64);
    int q = q0 + qi;
    int pos = nseg * s + off + q * r;
    _Float16* xr = Xh + (size_t)(b * 8192 + pos) * 768 + head * 64;
#pragma unroll
    for (int nf = 0; nf < 4; ++nf) {
      _Float16 hx = (_Float16)(acch[nf][rr] * invq);
      xr[nf * 16 + lc] = hx;
      cs[nf] += (float)hx;
    }
  }
#pragma unroll
  for (int nf = 0; nf < 4; ++nf) {
    cs[nf] += __shfl_xor(cs[nf], 16, 64);
    cs[nf] += __shfl_xor(cs[nf], 32, 64);
    if (lane < 16) wred[wid][nf * 16 + lc] = cs[nf];
  }
  __syncthreads();
  if (tid < 64) {
    float w4 = 0.f;
#pragma unroll
    for (int w = 0; w < 8; ++w) w4 += wred[w][tid];
    int slot = ((b * 12 + head) * 64 + nseg * 16 + qblk);
    partial[slot * 64 + tid] = w4;
  }
}

// div[b*768 + h*64 + d] = sum over this head's (nsegs*16) block partials
__global__ __launch_bounds__(256) void colsum2_kernel(const float* __restrict__ partial,
                                                      float* __restrict__ divbuf) {
  int i = blockIdx.x * 256 + threadIdx.x;  // 0..1535
  int b = i / 768, e = i % 768;
  int h = e >> 6, d = e & 63;
  int g = h >> 2;
  int nslots = 64 >> g;
  const float* src = partial + (size_t)((b * 12 + h) * 64) * 64 + d;
  float sacc = 0.f;
  for (int c = 0; c < nslots; ++c) sacc += src[c * 64];
  divbuf[i] = sacc;
}

// LayerNorm, wave-per-row: fp16 in/out, fuses /(div*3) + written-slot mask.
__global__ __launch_bounds__(256) void ln_kernel(const _Float16* __restrict__ Xh,
                                                 _Float16* __restrict__ Xln,
                                                 const float* __restrict__ divbuf,
                                                 const float* __restrict__ ln_w,
                                                 const float* __restrict__ ln_b) {
  int wid = threadIdx.x >> 6, lane = threadIdx.x & 63;
  int row = blockIdx.x * 4 + wid;
  int b = row >> 13, pos = row & 8191;
  float x[12];
  float s1 = 0.f, s2 = 0.f;
#pragma unroll
  for (int j = 0; j < 12; ++j) {
    int e = lane + 64 * j;
    int g = j >> 2;
    bool wr = (g == 0) || (g == 1 && (pos & 1) == 1) || (g == 2 && (pos & 3) == 2);
    float v = 0.f;
    if (wr) v = (float)Xh[(size_t)row * 768 + e] / (divbuf[b * 768 + e] * 3.0f);
    x[j] = v;
    s1 += v;
    s2 += v * v;
  }
#pragma unroll
  for (int msk = 1; msk < 64; msk <<= 1) {
    s1 += __shfl_xor(s1, msk, 64);
    s2 += __shfl_xor(s2, msk, 64);
  }
  float mean = s1 * (1.0f / 768.0f);
  float var = s2 * (1.0f / 768.0f) - mean * mean;
  float inv = rsqrtf(var + 1e-5f);
#pragma unroll
  for (int j = 0; j < 12; ++j) {
    int e = lane + 64 * j;
    Xln[(size_t)row * 768 + e] = (_Float16)((x[j] - mean) * inv * ln_w[e] + ln_b[e]);
  }
}

extern "C" void kernel_launch(void* const* d_in, const int* in_sizes, int n_in,
                              void* d_out, int out_size, void* d_ws, size_t ws_size,
                              hipStream_t stream) {
  const float* query = (const float*)d_in[0];
  const float* key   = (const float*)d_in[1];
  const float* value = (const float*)d_in[2];
  const float* Wq = (const float*)d_in[3];
  const float* bq = (const float*)d_in[4];
  const float* Wk = (const float*)d_in[5];
  const float* bk = (const float*)d_in[6];
  const float* Wv = (const float*)d_in[7];
  const float* bv = (const float*)d_in[8];
  const float* Wo = (const float*)d_in[9];
  const float* bo = (const float*)d_in[10];
  const float* ln_w = (const float*)d_in[11];
  const float* ln_b = (const float*)d_in[12];

  char* ws = (char*)d_ws;
  _Float16* Wsh = (_Float16*)ws; ws += (size_t)4 * 589824 * 2;
  _Float16* Wsl = (_Float16*)ws; ws += (size_t)4 * 589824 * 2;
  _Float16* Qhb = (_Float16*)ws; ws += (size_t)16384 * 768 * 2;
  _Float16* Qlb = (_Float16*)ws; ws += (size_t)16384 * 768 * 2;
  _Float16* Khb = (_Float16*)ws; ws += (size_t)16384 * 768 * 2;
  _Float16* Klb = (_Float16*)ws; ws += (size_t)16384 * 768 * 2;
  _Float16* Vth = (_Float16*)ws; ws += (size_t)7340032 * 2;
  _Float16* Vtl = (_Float16*)ws; ws += (size_t)7340032 * 2;
  char* Xregion = ws; ws += (size_t)16384 * 768 * 4;   // Xh + Xln (fp16 each)
  float* partial = (float*)ws; ws += (size_t)24 * 64 * 64 * 4;
  float* divbuf = (float*)ws; ws += 2 * 768 * 4;

  _Float16* Xh  = (_Float16*)Xregion;
  _Float16* Xln = Xh + (size_t)16384 * 768;
  _Float16* Aqh = (_Float16*)Xregion;
  _Float16* Aql = Aqh + (size_t)16384 * 768;

  size_t base_bytes = (size_t)(ws - (char*)d_ws);
  size_t extra = (size_t)4 * 16384 * 768 * 2;
  bool batched = ws_size >= base_bytes + extra;

  wsplit4_kernel<<<dim3(2304, 4), 256, 0, stream>>>(Wq, Wk, Wv, Wo, Wsh, Wsl);

  dim3 ggrid(6, 128);
  if (batched) {
    _Float16* Akh = (_Float16*)ws; ws += (size_t)16384 * 768 * 2;
    _Float16* Akl = (_Float16*)ws; ws += (size_t)16384 * 768 * 2;
    _Float16* Avh = (_Float16*)ws; ws += (size_t)16384 * 768 * 2;
    _Float16* Avl = (_Float16*)ws; ws += (size_t)16384 * 768 * 2;
    asplit3_kernel<<<dim3(6144, 3), 256, 0, stream>>>(query, key, value,
        Aqh, Aql, Akh, Akl, Avh, Avl);
    gemm3b_kernel<<<dim3(6, 384), 512, 0, stream>>>(
        Aqh, Aql, Akh, Akl, Avh, Avl, Wsh, Wsl, bq, bk, bv,
        Qhb, Qlb, Khb, Klb, Vth, Vtl);
  } else {
    asplit_kernel<<<6144, 256, 0, stream>>>(query, Aqh, Aql);
    gemm3_kernel<<<ggrid, 512, 0, stream>>>(Aqh, Aql, Wsh, Wsl, bq, Qhb, Qlb, 0);
    asplit_kernel<<<6144, 256, 0, stream>>>(key, Aqh, Aql);
    gemm3_kernel<<<ggrid, 512, 0, stream>>>(Aqh, Aql, Wsh + 589824, Wsl + 589824, bk, Khb, Klb, 0);
    asplit_kernel<<<6144, 256, 0, stream>>>(value, Aqh, Aql);
    gemm3_kernel<<<ggrid, 512, 0, stream>>>(Aqh, Aql, Wsh + 2 * 589824, Wsl + 2 * 589824, bv, Vth, Vtl, 1);
  }

  attn_kernel<<<896, 512, 0, stream>>>(Qhb, Qlb, Khb, Klb, Vth, Vtl, Xh, partial);

  colsum2_kernel<<<6, 256, 0, stream>>>(partial, divbuf);
  ln_kernel<<<4096, 256, 0, stream>>>(Xh, Xln, divbuf, ln_w, ln_b);

  gemm1_kernel<<<ggrid, 256, 0, stream>>>(Xln, Wsh + 3 * 589824, bo, (float*)d_out);
}

// Round 15
// 617.116 us; speedup vs baseline: 1.0425x; 1.0425x over previous
//
#include <hip/hip_runtime.h>

typedef __attribute__((ext_vector_type(4))) float f32x4;
typedef __attribute__((ext_vector_type(4))) unsigned int u32x4;
typedef __attribute__((ext_vector_type(8))) _Float16 half8;
typedef __attribute__((ext_vector_type(2))) _Float16 half2v;

__device__ inline f32x4 mfma_fp16(half8 a, half8 b, f32x4 c) {
  return __builtin_amdgcn_mfma_f32_16x16x32_f16(a, b, c, 0, 0, 0);
}

// XOR-swizzled element index, [rows][64 cols] fp16 tile (row stride 128B).
__device__ inline int kva(int row, int colbyte) {
  return ((row * 128 + colbyte) ^ ((row & 7) << 4)) >> 1;
}

// async global->LDS, 16B/lane; LDS dest = wave-uniform base + lane*16 (linear).
__device__ inline void gload16(const _Float16* g, _Float16* l) {
  __builtin_amdgcn_global_load_lds(
      (const __attribute__((address_space(1))) void*)g,
      (__attribute__((address_space(3))) void*)l, 16, 0, 0);
}

// All 4 weight matrices (K x N fp32) -> transposed fp16 hi/lo planes (N x K).
// lo = UNSCALED residual.
__global__ __launch_bounds__(256) void wsplit4_kernel(
    const float* __restrict__ Wq, const float* __restrict__ Wk,
    const float* __restrict__ Wv, const float* __restrict__ Wo,
    _Float16* __restrict__ Whi, _Float16* __restrict__ Wlo) {
  int w = blockIdx.y;
  const float* W = (w == 0) ? Wq : (w == 1) ? Wk : (w == 2) ? Wv : Wo;
  int i = blockIdx.x * 256 + threadIdx.x;
  int k = i / 768, n = i % 768;
  float v = W[i];
  _Float16 h = (_Float16)v;
  Whi[w * 589824 + n * 768 + k] = h;
  Wlo[w * 589824 + n * 768 + k] = (_Float16)(v - (float)h);
}

__device__ inline void asplit_body(const float* __restrict__ A,
                                   _Float16* __restrict__ Ahi,
                                   _Float16* __restrict__ Alo, int i) {
  f32x4 x0 = *(const f32x4*)(A + i);
  f32x4 x1 = *(const f32x4*)(A + i + 4);
  half8 vh, vl;
#pragma unroll
  for (int j = 0; j < 4; ++j) {
    _Float16 h0 = (_Float16)x0[j];
    vh[j] = h0; vl[j] = (_Float16)(x0[j] - (float)h0);
    _Float16 h1 = (_Float16)x1[j];
    vh[4 + j] = h1; vl[4 + j] = (_Float16)(x1[j] - (float)h1);
  }
  *(half8*)(Ahi + i) = vh;
  *(half8*)(Alo + i) = vl;
}

__global__ __launch_bounds__(256) void asplit_kernel(const float* __restrict__ A,
                                                     _Float16* __restrict__ Ahi,
                                                     _Float16* __restrict__ Alo) {
  asplit_body(A, Ahi, Alo, (blockIdx.x * 256 + threadIdx.x) * 8);
}

__global__ __launch_bounds__(256) void asplit3_kernel(
    const float* __restrict__ Aq, const float* __restrict__ Ak,
    const float* __restrict__ Av,
    _Float16* __restrict__ Aqh, _Float16* __restrict__ Aql,
    _Float16* __restrict__ Akh, _Float16* __restrict__ Akl,
    _Float16* __restrict__ Avh, _Float16* __restrict__ Avl) {
  int w = blockIdx.y;
  const float* A = (w == 0) ? Aq : (w == 1) ? Ak : Av;
  _Float16* H = (w == 0) ? Aqh : (w == 1) ? Akh : Avh;
  _Float16* L = (w == 0) ? Aql : (w == 1) ? Akl : Avl;
  asplit_body(A, H, L, (blockIdx.x * 256 + threadIdx.x) * 8);
}

// Vt plane base (in elements) for (b, head). Per-b size = 3,670,016 elems.
__device__ inline int vt_base(int b, int h) {
  int base = b * 3670016;
  if (h < 4)      base += h * 524288;
  else if (h < 8) base += 2097152 + (h - 4) * 262144;
  else            base += 3145728 + (h - 8) * 131072;
  return base;
}

// High-precision GEMM core (R13 form — BK=64, (512,2); BK=32 regressed in R14:
// barrier-amortization loss > occupancy gain. Structure is at the ~900TF
// 2-barrier ceiling; leave it).
__device__ __forceinline__ void gemm3_core(
    const _Float16* __restrict__ Ahi, const _Float16* __restrict__ Alo,
    const _Float16* __restrict__ Bhi, const _Float16* __restrict__ Blo,
    const float* __restrict__ bias, _Float16* __restrict__ Chi,
    _Float16* __restrict__ Clo, int mode, int m0, int n0,
    _Float16* Ah, _Float16* Al, _Float16* Bh, _Float16* Bl) {
  int tid = threadIdx.x;
  int lane = tid & 63, wid = tid >> 6;
  int wm = wid >> 1, wn = wid & 1;
  int lg = lane >> 4, lc = lane & 15;

  f32x4 acc[2][4] = {};

  size_t sA[2], sB[2];
  int ldst[2];
#pragma unroll
  for (int c = 0; c < 2; ++c) {
    int idxv = c * 512 + tid;
    int m = idxv >> 3;
    int ke = ((idxv & 7) << 3) ^ ((m & 7) << 3);
    sA[c] = (size_t)(m0 + m) * 768 + ke;
    sB[c] = (size_t)(n0 + m) * 768 + ke;
    ldst[c] = (c * 512 + wid * 64) * 8;
  }

  for (int k0 = 0; k0 < 768; k0 += 64) {
    __syncthreads();
#pragma unroll
    for (int c = 0; c < 2; ++c) {
      gload16(Ahi + sA[c] + k0, Ah + ldst[c]);
      gload16(Alo + sA[c] + k0, Al + ldst[c]);
      gload16(Bhi + sB[c] + k0, Bh + ldst[c]);
      gload16(Blo + sB[c] + k0, Bl + ldst[c]);
    }
    __syncthreads();

#pragma unroll
    for (int ks = 0; ks < 2; ++ks) {
      half8 ah[2], al[2], bh[4], bl[4];
#pragma unroll
      for (int mt = 0; mt < 2; ++mt) {
        int ro = kva(wm * 32 + mt * 16 + lc, ks * 64 + (lg << 4));
        ah[mt] = *(half8*)(&Ah[ro]);
        al[mt] = *(half8*)(&Al[ro]);
      }
#pragma unroll
      for (int nf = 0; nf < 4; ++nf) {
        int ro = kva(wn * 64 + nf * 16 + lc, ks * 64 + (lg << 4));
        bh[nf] = *(half8*)(&Bh[ro]);
        bl[nf] = *(half8*)(&Bl[ro]);
      }
#pragma unroll
      for (int mt = 0; mt < 2; ++mt)
#pragma unroll
        for (int nf = 0; nf < 4; ++nf) {
          acc[mt][nf] = mfma_fp16(al[mt], bh[nf], acc[mt][nf]);
          acc[mt][nf] = mfma_fp16(ah[mt], bl[nf], acc[mt][nf]);
          acc[mt][nf] = mfma_fp16(ah[mt], bh[nf], acc[mt][nf]);
        }
    }
  }

#pragma unroll
  for (int mt = 0; mt < 2; ++mt)
#pragma unroll
    for (int nf = 0; nf < 4; ++nf) {
      int col = n0 + wn * 64 + nf * 16 + lc;
      int row0 = m0 + wm * 32 + mt * 16 + (lg << 2);
      float bv = bias[col];
#pragma unroll
      for (int rr = 0; rr < 4; ++rr) {
        int row = row0 + rr;
        float v = acc[mt][nf][rr] + bv;
        _Float16 h = (_Float16)v;
        _Float16 l = (_Float16)(v - (float)h);
        if (mode == 0) {
          Chi[(size_t)row * 768 + col] = h;
          Clo[(size_t)row * 768 + col] = l;
        } else {
          int b = row >> 13, pos = row & 8191;
          int hh = col >> 6, d = col & 63;
          int g = hh >> 2;
          int rdil = 1 << g;
          if ((pos & (rdil - 1)) == g) {
            int t = (pos - g) >> g;
            int Ng = 8192 >> g;
            Chi[vt_base(b, hh) + d * Ng + t] = h;
            Clo[vt_base(b, hh) + d * Ng + t] = l;
          }
        }
      }
    }
}

// fallback: one projection per launch (2D grid, no swizzle)
__global__ __launch_bounds__(512, 2) void gemm3_kernel(
    const _Float16* __restrict__ Ahi, const _Float16* __restrict__ Alo,
    const _Float16* __restrict__ Bhi, const _Float16* __restrict__ Blo,
    const float* __restrict__ bias,
    _Float16* __restrict__ Chi, _Float16* __restrict__ Clo, int mode) {
  __shared__ _Float16 Ah[128 * 64], Al[128 * 64], Bh[128 * 64], Bl[128 * 64];
  gemm3_core(Ahi, Alo, Bhi, Blo, bias, Chi, Clo, mode,
             blockIdx.y * 128, blockIdx.x * 128, Ah, Al, Bh, Bl);
}

// batched: all three projections, 1D grid 2304, XCD-chunked (288/XCD) so the
// 6 n-blocks sharing an A-row panel land on ONE XCD's L2 (T1, bijective).
__global__ __launch_bounds__(512, 2) void gemm3b_kernel(
    const _Float16* __restrict__ Aqh, const _Float16* __restrict__ Aql,
    const _Float16* __restrict__ Akh, const _Float16* __restrict__ Akl,
    const _Float16* __restrict__ Avh, const _Float16* __restrict__ Avl,
    const _Float16* __restrict__ Wsh, const _Float16* __restrict__ Wsl,
    const float* __restrict__ bq, const float* __restrict__ bk,
    const float* __restrict__ bv,
    _Float16* __restrict__ Qhb, _Float16* __restrict__ Qlb,
    _Float16* __restrict__ Khb, _Float16* __restrict__ Klb,
    _Float16* __restrict__ Vth, _Float16* __restrict__ Vtl) {
  __shared__ _Float16 Ah[128 * 64], Al[128 * 64], Bh[128 * 64], Bl[128 * 64];
  int orig = blockIdx.x;                    // 0..2303, nwg%8==0
  int wg = (orig & 7) * 288 + (orig >> 3);  // bijective XCD chunking
  int sec = wg / 768, rem = wg % 768;
  int m0 = (rem / 6) * 128, n0 = (rem % 6) * 128;
  const _Float16* Ahi = (sec == 0) ? Aqh : (sec == 1) ? Akh : Avh;
  const _Float16* Alo = (sec == 0) ? Aql : (sec == 1) ? Akl : Avl;
  const float* bias = (sec == 0) ? bq : (sec == 1) ? bk : bv;
  _Float16* Chi = (sec == 0) ? Qhb : (sec == 1) ? Khb : Vth;
  _Float16* Clo = (sec == 0) ? Qlb : (sec == 1) ? Klb : Vtl;
  gemm3_core(Ahi, Alo, Wsh + sec * 589824, Wsl + sec * 589824, bias,
             Chi, Clo, (sec == 2) ? 1 : 0, m0, n0, Ah, Al, Bh, Bl);
}

// Output projection: C(fp32) = A(fp16) @ Wt^T + bias. 1D grid 768, XCD-chunked.
__global__ __launch_bounds__(256, 4) void gemm1_kernel(
    const _Float16* __restrict__ A, const _Float16* __restrict__ Bt,
    const float* __restrict__ bias, float* __restrict__ C) {
  __shared__ _Float16 As[128 * 64];
  __shared__ _Float16 Bs[128 * 64];
  int orig = blockIdx.x;                    // 0..767
  int wg = (orig & 7) * 96 + (orig >> 3);   // bijective XCD chunking
  int m0 = (wg / 6) * 128, n0 = (wg % 6) * 128;
  int tid = threadIdx.x;
  int lane = tid & 63, wid = tid >> 6;
  int wm = wid >> 1, wn = wid & 1;
  int lg = lane >> 4, lc = lane & 15;

  f32x4 acc[4][4] = {};

  size_t sA[4], sB[4];
  int ldst[4];
#pragma unroll
  for (int c = 0; c < 4; ++c) {
    int idxv = c * 256 + tid;
    int m = idxv >> 3;
    int ke = ((idxv & 7) << 3) ^ ((m & 7) << 3);
    sA[c] = (size_t)(m0 + m) * 768 + ke;
    sB[c] = (size_t)(n0 + m) * 768 + ke;
    ldst[c] = (c * 256 + wid * 64) * 8;
  }

  for (int k0 = 0; k0 < 768; k0 += 64) {
    __syncthreads();
#pragma unroll
    for (int c = 0; c < 4; ++c) {
      gload16(A + sA[c] + k0, As + ldst[c]);
      gload16(Bt + sB[c] + k0, Bs + ldst[c]);
    }
    __syncthreads();
#pragma unroll
    for (int ks = 0; ks < 2; ++ks) {
      half8 af[4], bf[4];
#pragma unroll
      for (int mt = 0; mt < 4; ++mt)
        af[mt] = *(half8*)(&As[kva(wm * 64 + mt * 16 + lc, ks * 64 + (lg << 4))]);
#pragma unroll
      for (int nf = 0; nf < 4; ++nf)
        bf[nf] = *(half8*)(&Bs[kva(wn * 64 + nf * 16 + lc, ks * 64 + (lg << 4))]);
#pragma unroll
      for (int mt = 0; mt < 4; ++mt)
#pragma unroll
        for (int nf = 0; nf < 4; ++nf)
          acc[mt][nf] = mfma_fp16(af[mt], bf[nf], acc[mt][nf]);
    }
  }

#pragma unroll
  for (int mt = 0; mt < 4; ++mt)
#pragma unroll
    for (int nf = 0; nf < 4; ++nf) {
      int col = n0 + wn * 64 + nf * 16 + lc;
      int row0 = m0 + wm * 64 + mt * 16 + (lg << 2);
      float bv = bias[col];
#pragma unroll
      for (int rr = 0; rr < 4; ++rr)
        C[(size_t)(row0 + rr) * 768 + col] = acc[mt][nf][rr] + bv;
    }
}

// Single-pass dilated flash attention, fp16-pair precision, merged accumulator.
// SWAPPED QK^T; PV A-frags via in-wave shfl; fp16 X; fused colsum stage 1.
__global__ __launch_bounds__(512, 4) void attn_kernel(
    const _Float16* __restrict__ Qh, const _Float16* __restrict__ Ql,
    const _Float16* __restrict__ Kh, const _Float16* __restrict__ Kl,
    const _Float16* __restrict__ Vth, const _Float16* __restrict__ Vtl,
    _Float16* __restrict__ Xh, float* __restrict__ partial) {
  __shared__ _Float16 Ksh[64 * 64], Ksl[64 * 64];   // XOR-swizzled, stride 64
  __shared__ _Float16 Vsh[64 * 64], Vsl[64 * 64];
  __shared__ float wred[8][64];

  int bid = blockIdx.x;
  int xcd = bid & 7, idx = bid >> 3;
  int u_glob = xcd * 7 + (idx >> 4);
  int qblk = idx & 15;
  int g = (u_glob < 32) ? 0 : (u_glob < 48) ? 1 : 2;
  int u = (g == 0) ? u_glob : (g == 1) ? u_glob - 32 : u_glob - 48;
  int nsegs = 4 >> g;
  int b = u / (nsegs * 4), rem = u % (nsegs * 4);
  int nseg = rem >> 2, hg = rem & 3;
  int head = g * 4 + hg;
  int s = 2048 << g, r = 1 << g, off = g;
  int Ng = 8192 >> g;
  int tbase = nseg * 2048;
  int vbase = vt_base(b, head);

  int tid = threadIdx.x, lane = tid & 63, wid = tid >> 6;
  int lg = lane >> 4, lc = lane & 15;

  int q0 = qblk * 128 + wid * 16;
  half8 qfh[2], qfl[2];
  {
    int q = q0 + lc;
    int pos = nseg * s + off + q * r;
    size_t ro = (size_t)(b * 8192 + pos) * 768 + head * 64;
#pragma unroll
    for (int ks = 0; ks < 2; ++ks) {
      qfh[ks] = *(const half8*)(Qh + ro + ks * 32 + (lg << 3));
      qfl[ks] = *(const half8*)(Ql + ro + ks * 32 + (lg << 3));
    }
  }

  int kr = tid >> 3, kcb = (tid & 7) << 4;
  const int kc = (tid & 7) << 3;
  size_t kro = (size_t)(b * 8192 + nseg * s + off + kr * r) * 768 + head * 64 + kc;
  size_t vro = (size_t)vbase + (size_t)kr * Ng + tbase + kc;
  const size_t kstep = (size_t)64 * r * 768;
  _Float16* KshW = &Ksh[kva(kr, kcb)];
  _Float16* KslW = &Ksl[kva(kr, kcb)];
  _Float16* VshW = &Vsh[kva(kr, kcb)];
  _Float16* VslW = &Vsl[kva(kr, kcb)];

  f32x4 acch[4] = {};
  float lsum = 0.f;

  const int sl0 = ((lane & 16) << 1) + lc;
  const int sl1 = sl0 + 16;
  const bool hiSel = (lane & 32) != 0;

  half8 rKh = *(const half8*)(Kh + kro);
  half8 rKl = *(const half8*)(Kl + kro);
  half8 rVh = *(const half8*)(Vth + vro);
  half8 rVl = *(const half8*)(Vtl + vro);
  kro += kstep;
  vro += 64;

  for (int kt = 0; kt < 32; ++kt) {
    __syncthreads();
    *(half8*)KshW = rKh;
    *(half8*)KslW = rKl;
    *(half8*)VshW = rVh;
    *(half8*)VslW = rVl;
    if (kt < 31) {
      rKh = *(const half8*)(Kh + kro);
      rKl = *(const half8*)(Kl + kro);
      rVh = *(const half8*)(Vth + vro);
      rVl = *(const half8*)(Vtl + vro);
      kro += kstep;
      vro += 64;
    }
    __syncthreads();

    f32x4 sc[4];
#pragma unroll
    for (int nf = 0; nf < 4; ++nf) {
      half8 kh[2], kl[2];
#pragma unroll
      for (int ks = 0; ks < 2; ++ks) {
        int ro = kva(nf * 16 + lc, ks * 64 + (lg << 4));
        kh[ks] = *(half8*)(&Ksh[ro]);
        kl[ks] = *(half8*)(&Ksl[ro]);
      }
      f32x4 t = {};
#pragma unroll
      for (int ks = 0; ks < 2; ++ks) {
        t = mfma_fp16(kl[ks], qfh[ks], t);
        t = mfma_fp16(kh[ks], qfl[ks], t);
      }
#pragma unroll
      for (int ks = 0; ks < 2; ++ks)
        t = mfma_fp16(kh[ks], qfh[ks], t);
      sc[nf] = t;
    }

    unsigned int pk[4][2];
#pragma unroll
    for (int nf = 0; nf < 4; ++nf) {
      _Float16 hh[4];
#pragma unroll
      for (int rr = 0; rr < 4; ++rr) {
        float p = __expf(sc[nf][rr] * 0.125f);
        hh[rr] = (_Float16)p;
        lsum += (float)hh[rr];
      }
      half2v p01 = {hh[0], hh[1]};
      half2v p23 = {hh[2], hh[3]};
      pk[nf][0] = __builtin_bit_cast(unsigned int, p01);
      pk[nf][1] = __builtin_bit_cast(unsigned int, p23);
    }

#pragma unroll
    for (int ks2 = 0; ks2 < 2; ++ks2) {
      int nfA = 2 * ks2, nfB = 2 * ks2 + 1;
      unsigned int a0 = __shfl(pk[nfA][0], sl0, 64);
      unsigned int b0 = __shfl(pk[nfB][0], sl0, 64);
      unsigned int a1 = __shfl(pk[nfA][1], sl0, 64);
      unsigned int b1 = __shfl(pk[nfB][1], sl0, 64);
      unsigned int a2 = __shfl(pk[nfA][0], sl1, 64);
      unsigned int b2 = __shfl(pk[nfB][0], sl1, 64);
      unsigned int a3 = __shfl(pk[nfA][1], sl1, 64);
      unsigned int b3 = __shfl(pk[nfB][1], sl1, 64);
      u32x4 pw;
      pw[0] = hiSel ? b0 : a0;
      pw[1] = hiSel ? b1 : a1;
      pw[2] = hiSel ? b2 : a2;
      pw[3] = hiSel ? b3 : a3;
      half8 pa = __builtin_bit_cast(half8, pw);
#pragma unroll
      for (int nf = 0; nf < 4; ++nf) {
        int ro = kva(nf * 16 + lc, ks2 * 64 + (lg << 4));
        half8 vh = *(half8*)(&Vsh[ro]);
        half8 vl = *(half8*)(&Vsl[ro]);
        acch[nf] = mfma_fp16(pa, vl, acch[nf]);
        acch[nf] = mfma_fp16(pa, vh, acch[nf]);
      }
    }
  }

  lsum += __shfl_xor(lsum, 16, 64);
  lsum += __shfl_xor(lsum, 32, 64);
  float inv_l = 1.0f / lsum;

  float cs[4] = {};
#pragma unroll
  for (int rr = 0; rr < 4; ++rr) {
    int qi = ((lane >> 4) & 3) * 4 + rr;
    float invq = __shfl(inv_l, (lane & 48) + qi, 64);
    int q = q0 + qi;
    int pos = nseg * s + off + q * r;
    _Float16* xr = Xh + (size_t)(b * 8192 + pos) * 768 + head * 64;
#pragma unroll
    for (int nf = 0; nf < 4; ++nf) {
      _Float16 hx = (_Float16)(acch[nf][rr] * invq);
      xr[nf * 16 + lc] = hx;
      cs[nf] += (float)hx;
    }
  }
#pragma unroll
  for (int nf = 0; nf < 4; ++nf) {
    cs[nf] += __shfl_xor(cs[nf], 16, 64);
    cs[nf] += __shfl_xor(cs[nf], 32, 64);
    if (lane < 16) wred[wid][nf * 16 + lc] = cs[nf];
  }
  __syncthreads();
  if (tid < 64) {
    float w4 = 0.f;
#pragma unroll
    for (int w = 0; w < 8; ++w) w4 += wred[w][tid];
    int slot = ((b * 12 + head) * 64 + nseg * 16 + qblk);
    partial[slot * 64 + tid] = w4;
  }
}

// div[b*768 + h*64 + d] = sum over this head's (nsegs*16) block partials
__global__ __launch_bounds__(256) void colsum2_kernel(const float* __restrict__ partial,
                                                      float* __restrict__ divbuf) {
  int i = blockIdx.x * 256 + threadIdx.x;  // 0..1535
  int b = i / 768, e = i % 768;
  int h = e >> 6, d = e & 63;
  int g = h >> 2;
  int nslots = 64 >> g;
  const float* src = partial + (size_t)((b * 12 + h) * 64) * 64 + d;
  float sacc = 0.f;
  for (int c = 0; c < nslots; ++c) sacc += src[c * 64];
  divbuf[i] = sacc;
}

// LayerNorm, wave-per-row: fp16 in/out, fuses /(div*3) + written-slot mask.
__global__ __launch_bounds__(256) void ln_kernel(const _Float16* __restrict__ Xh,
                                                 _Float16* __restrict__ Xln,
                                                 const float* __restrict__ divbuf,
                                                 const float* __restrict__ ln_w,
                                                 const float* __restrict__ ln_b) {
  int wid = threadIdx.x >> 6, lane = threadIdx.x & 63;
  int row = blockIdx.x * 4 + wid;
  int b = row >> 13, pos = row & 8191;
  float x[12];
  float s1 = 0.f, s2 = 0.f;
#pragma unroll
  for (int j = 0; j < 12; ++j) {
    int e = lane + 64 * j;
    int g = j >> 2;
    bool wr = (g == 0) || (g == 1 && (pos & 1) == 1) || (g == 2 && (pos & 3) == 2);
    float v = 0.f;
    if (wr) v = (float)Xh[(size_t)row * 768 + e] / (divbuf[b * 768 + e] * 3.0f);
    x[j] = v;
    s1 += v;
    s2 += v * v;
  }
#pragma unroll
  for (int msk = 1; msk < 64; msk <<= 1) {
    s1 += __shfl_xor(s1, msk, 64);
    s2 += __shfl_xor(s2, msk, 64);
  }
  float mean = s1 * (1.0f / 768.0f);
  float var = s2 * (1.0f / 768.0f) - mean * mean;
  float inv = rsqrtf(var + 1e-5f);
#pragma unroll
  for (int j = 0; j < 12; ++j) {
    int e = lane + 64 * j;
    Xln[(size_t)row * 768 + e] = (_Float16)((x[j] - mean) * inv * ln_w[e] + ln_b[e]);
  }
}

extern "C" void kernel_launch(void* const* d_in, const int* in_sizes, int n_in,
                              void* d_out, int out_size, void* d_ws, size_t ws_size,
                              hipStream_t stream) {
  const float* query = (const float*)d_in[0];
  const float* key   = (const float*)d_in[1];
  const float* value = (const float*)d_in[2];
  const float* Wq = (const float*)d_in[3];
  const float* bq = (const float*)d_in[4];
  const float* Wk = (const float*)d_in[5];
  const float* bk = (const float*)d_in[6];
  const float* Wv = (const float*)d_in[7];
  const float* bv = (const float*)d_in[8];
  const float* Wo = (const float*)d_in[9];
  const float* bo = (const float*)d_in[10];
  const float* ln_w = (const float*)d_in[11];
  const float* ln_b = (const float*)d_in[12];

  char* ws = (char*)d_ws;
  _Float16* Wsh = (_Float16*)ws; ws += (size_t)4 * 589824 * 2;
  _Float16* Wsl = (_Float16*)ws; ws += (size_t)4 * 589824 * 2;
  _Float16* Qhb = (_Float16*)ws; ws += (size_t)16384 * 768 * 2;
  _Float16* Qlb = (_Float16*)ws; ws += (size_t)16384 * 768 * 2;
  _Float16* Khb = (_Float16*)ws; ws += (size_t)16384 * 768 * 2;
  _Float16* Klb = (_Float16*)ws; ws += (size_t)16384 * 768 * 2;
  _Float16* Vth = (_Float16*)ws; ws += (size_t)7340032 * 2;
  _Float16* Vtl = (_Float16*)ws; ws += (size_t)7340032 * 2;
  char* Xregion = ws; ws += (size_t)16384 * 768 * 4;   // Xh + Xln (fp16 each)
  float* partial = (float*)ws; ws += (size_t)24 * 64 * 64 * 4;
  float* divbuf = (float*)ws; ws += 2 * 768 * 4;

  _Float16* Xh  = (_Float16*)Xregion;
  _Float16* Xln = Xh + (size_t)16384 * 768;
  _Float16* Aqh = (_Float16*)Xregion;
  _Float16* Aql = Aqh + (size_t)16384 * 768;

  size_t base_bytes = (size_t)(ws - (char*)d_ws);
  size_t extra = (size_t)4 * 16384 * 768 * 2;
  bool batched = ws_size >= base_bytes + extra;

  wsplit4_kernel<<<dim3(2304, 4), 256, 0, stream>>>(Wq, Wk, Wv, Wo, Wsh, Wsl);

  dim3 ggrid(6, 128);
  if (batched) {
    _Float16* Akh = (_Float16*)ws; ws += (size_t)16384 * 768 * 2;
    _Float16* Akl = (_Float16*)ws; ws += (size_t)16384 * 768 * 2;
    _Float16* Avh = (_Float16*)ws; ws += (size_t)16384 * 768 * 2;
    _Float16* Avl = (_Float16*)ws; ws += (size_t)16384 * 768 * 2;
    asplit3_kernel<<<dim3(6144, 3), 256, 0, stream>>>(query, key, value,
        Aqh, Aql, Akh, Akl, Avh, Avl);
    gemm3b_kernel<<<2304, 512, 0, stream>>>(
        Aqh, Aql, Akh, Akl, Avh, Avl, Wsh, Wsl, bq, bk, bv,
        Qhb, Qlb, Khb, Klb, Vth, Vtl);
  } else {
    asplit_kernel<<<6144, 256, 0, stream>>>(query, Aqh, Aql);
    gemm3_kernel<<<ggrid, 512, 0, stream>>>(Aqh, Aql, Wsh, Wsl, bq, Qhb, Qlb, 0);
    asplit_kernel<<<6144, 256, 0, stream>>>(key, Aqh, Aql);
    gemm3_kernel<<<ggrid, 512, 0, stream>>>(Aqh, Aql, Wsh + 589824, Wsl + 589824, bk, Khb, Klb, 0);
    asplit_kernel<<<6144, 256, 0, stream>>>(value, Aqh, Aql);
    gemm3_kernel<<<ggrid, 512, 0, stream>>>(Aqh, Aql, Wsh + 2 * 589824, Wsl + 2 * 589824, bv, Vth, Vtl, 1);
  }

  attn_kernel<<<896, 512, 0, stream>>>(Qhb, Qlb, Khb, Klb, Vth, Vtl, Xh, partial);

  colsum2_kernel<<<6, 256, 0, stream>>>(partial, divbuf);
  ln_kernel<<<4096, 256, 0, stream>>>(Xh, Xln, divbuf, ln_w, ln_b);

  gemm1_kernel<<<768, 256, 0, stream>>>(Xln, Wsh + 3 * 589824, bo, (float*)d_out);
}